// Round 6
// baseline (141.450 us; speedup 1.0000x reference)
//
#include <hip/hip_runtime.h>
#include <cstdint>

typedef unsigned short u16;
typedef __bf16 bf16x8 __attribute__((ext_vector_type(8)));
typedef float f32x4 __attribute__((ext_vector_type(4)));
typedef u16 u16x8 __attribute__((ext_vector_type(8)));

// Sizes fixed by reference: B=8, S=2048, I=256, H=256, M=1024
#define NX 4194304L   // key elems (16384*256)

__device__ __forceinline__ u16 f2bf(float f) {
  union { float f; uint32_t u; } v; v.f = f;
  uint32_t r = v.u + 0x7fffu + ((v.u >> 16) & 1u);
  return (u16)(r >> 16);
}

__device__ __forceinline__ u16x8 cvt8(float4 a, float4 b) {
  u16x8 o;
  o[0]=f2bf(a.x); o[1]=f2bf(a.y); o[2]=f2bf(a.z); o[3]=f2bf(a.w);
  o[4]=f2bf(b.x); o[5]=f2bf(b.y); o[6]=f2bf(b.z); o[7]=f2bf(b.w);
  return o;
}

// bf16 128x256 LDS tile swizzle (16B-chunk XOR) — keeps b128 ops conflict-free.
__device__ __forceinline__ int sw_addr(int row, int k) {
  return row * 256 + ((((k >> 3) ^ (row & 7)) << 3)) + (k & 7);
}

// ---------------------------------------------------------------------------
// GEMM1: key = relu(x @ W^T), M=16384 N=256 K=256, fp32 in / fp32 out.
// Proven R3/R4 structure (~13 us fitted): W-tile (128 x K=256) staged ONCE to
// LDS as bf16 (one barrier), then a barrier-free K-loop streams x straight
// into MFMA A-fragments (16B/lane, perfectly coalesced) with in-register cvt.
// Grid (2,128) = 256 blocks; 64 KB LDS -> 2 blocks/CU, 8 waves/CU.
// ---------------------------------------------------------------------------
__global__ __launch_bounds__(256, 2)
void gemm1_kernel(const float* __restrict__ x, const float* __restrict__ W,
                  float* __restrict__ key_f)
{
  constexpr int K = 256;
  __shared__ __align__(16) u16 sB[128 * 256];   // 64 KB

  const int tid  = threadIdx.x;
  const int wave = tid >> 6;
  const int lane = tid & 63;
  const int quad = lane >> 4;
  const int r    = lane & 15;
  const int wm   = wave >> 1;
  const int wn   = wave & 1;
  const int bm   = blockIdx.y * 128;
  const int bn   = blockIdx.x * 128;

  // stage W tile (128 rows x 256 K) fp32 -> bf16, once
  {
    const int rowS = tid >> 1;
    const int colS = (tid & 1) * 16;
    const float* Bg = W + (long)(bn + rowS) * K + colS;
    #pragma unroll
    for (int c = 0; c < 8; ++c) {
      const float* p = Bg + c * 32;
      float4 f0 = *(const float4*)(p);
      float4 f1 = *(const float4*)(p + 4);
      float4 f2 = *(const float4*)(p + 8);
      float4 f3 = *(const float4*)(p + 12);
      const int col = colS + c * 32;
      *(u16x8*)(sB + sw_addr(rowS, col))     = cvt8(f0, f1);
      *(u16x8*)(sB + sw_addr(rowS, col + 8)) = cvt8(f2, f3);
    }
  }
  __syncthreads();   // the only barrier

  const float* Af = x + (long)(bm + wm * 64 + r) * K;

  f32x4 acc[4][4];
  #pragma unroll
  for (int i = 0; i < 4; i++)
    #pragma unroll
    for (int j = 0; j < 4; j++)
      acc[i][j] = f32x4{0.f, 0.f, 0.f, 0.f};

  #pragma unroll 2
  for (int kt = 0; kt < K; kt += 32) {
    bf16x8 af[4], bf[4];
    #pragma unroll
    for (int i = 0; i < 4; ++i) {
      const float* p = Af + (long)i * 16 * K + kt + quad * 8;
      float4 a0 = *(const float4*)(p);
      float4 a1 = *(const float4*)(p + 4);
      u16x8 t = cvt8(a0, a1);
      af[i] = *(bf16x8*)&t;
    }
    #pragma unroll
    for (int j = 0; j < 4; ++j)
      bf[j] = *(const bf16x8*)(sB + sw_addr(wn * 64 + j * 16 + r, kt + quad * 8));
    #pragma unroll
    for (int i = 0; i < 4; ++i)
      #pragma unroll
      for (int j = 0; j < 4; ++j)
        acc[i][j] = __builtin_amdgcn_mfma_f32_16x16x32_bf16(af[i], bf[j], acc[i][j], 0, 0, 0);
  }

  // epilogue: C/D layout col=lane&15, row=quad*4+reg (verified m89/m91)
  #pragma unroll
  for (int i = 0; i < 4; i++)
    #pragma unroll
    for (int j = 0; j < 4; j++)
      #pragma unroll
      for (int reg = 0; reg < 4; reg++) {
        const int row = bm + wm * 64 + i * 16 + quad * 4 + reg;
        const int col = bn + wn * 64 + j * 16 + r;
        float v = acc[i][j][reg];
        key_f[(long)row * 256 + col] = v > 0.f ? v : 0.f;
      }
}

// ---------------------------------------------------------------------------
// GEMM2: val_b = key_b @ mem_b^T, per batch M=2048 N=1024 K=256.
// m97 2-barrier global_load_lds K-loop staging RAW FP32 tiles (128x32 fp32 =
// 16 KB each; 32 KB LDS -> up to 5 blocks/CU). global_load_lds forces LDS
// slot = base + lane*16 with a per-lane GLOBAL address, so logical 16B-chunk
// lc of row rw is sourced from global chunk lc ^ (rw&7); frag reads undo the
// XOR -> 2-way bank aliasing = free (m136). fp32->bf16 happens at frag-read
// (cvt8) — staging pattern verbatim from R5's verified gemm1.
// Reads key fp32 straight from d_out and mem fp32 from d_in: no ws, no
// convert kernel; operand re-reads are L2/L3-served (total operands ~49 MB
// << 256 MB Infinity Cache; R4 measured FETCH 21 MB on the bf16 variant).
// ---------------------------------------------------------------------------
__global__ __launch_bounds__(256, 2)
void gemm2_kernel(const float* __restrict__ key_f, const float* __restrict__ mem,
                  float* __restrict__ val_f)
{
  constexpr int K = 256;
  __shared__ __align__(16) float sA[128 * 32];   // 16 KB
  __shared__ __align__(16) float sB[128 * 32];   // 16 KB

  const int tid  = threadIdx.x;
  const int wave = tid >> 6;
  const int lane = tid & 63;
  const int quad = lane >> 4;
  const int r    = lane & 15;
  const int wm   = wave >> 1;
  const int wn   = wave & 1;
  const int bm   = blockIdx.y * 128;
  const int bn   = blockIdx.x * 128;
  const int batch = blockIdx.z;

  const char* Ab = (const char*)(key_f + (long)batch * 2048 * 256);
  const char* Bb = (const char*)(mem   + (long)batch * 1024 * 256);

  const int o_base = wave * 1024 + lane * 16;   // this lane's LDS byte slot

  f32x4 acc[4][4];
  #pragma unroll
  for (int i = 0; i < 4; i++)
    #pragma unroll
    for (int j = 0; j < 4; j++)
      acc[i][j] = f32x4{0.f, 0.f, 0.f, 0.f};

  for (int kt = 0; kt < K; kt += 32) {
    __syncthreads();   // previous iteration's frag reads done
    #pragma unroll
    for (int rr = 0; rr < 4; rr++) {
      const int o   = rr * 4096 + o_base;
      const int row = o >> 7;            // 128 B per fp32 row (32 fp32)
      const int cp  = (o >> 4) & 7;      // LDS slot chunk within row
      const int c   = cp ^ (row & 7);    // global source chunk (XOR swizzle)
      const char* ga = Ab + (long)(bm + row) * 1024 + kt * 4 + c * 16;
      const char* gb = Bb + (long)(bn + row) * 1024 + kt * 4 + c * 16;
      char* la = (char*)sA + rr * 4096 + wave * 1024;
      char* lb = (char*)sB + rr * 4096 + wave * 1024;
      __builtin_amdgcn_global_load_lds((const __attribute__((address_space(1))) void*)ga,
                                       (__attribute__((address_space(3))) void*)la, 16, 0, 0);
      __builtin_amdgcn_global_load_lds((const __attribute__((address_space(1))) void*)gb,
                                       (__attribute__((address_space(3))) void*)lb, 16, 0, 0);
    }
    __syncthreads();   // vmcnt(0) drained before barrier -> LDS valid

    bf16x8 af[4], bfr[4];
    const int s = r & 7;
    #pragma unroll
    for (int i = 0; i < 4; ++i) {
      const float* base = sA + (wm * 64 + i * 16 + r) * 32;
      float4 f0 = *(const float4*)(base + (((2 * quad)     ^ s) << 2));
      float4 f1 = *(const float4*)(base + (((2 * quad + 1) ^ s) << 2));
      u16x8 t = cvt8(f0, f1);
      af[i] = *(bf16x8*)&t;
    }
    #pragma unroll
    for (int j = 0; j < 4; ++j) {
      const float* base = sB + (wn * 64 + j * 16 + r) * 32;
      float4 f0 = *(const float4*)(base + (((2 * quad)     ^ s) << 2));
      float4 f1 = *(const float4*)(base + (((2 * quad + 1) ^ s) << 2));
      u16x8 t = cvt8(f0, f1);
      bfr[j] = *(bf16x8*)&t;
    }
    #pragma unroll
    for (int i = 0; i < 4; ++i)
      #pragma unroll
      for (int j = 0; j < 4; ++j)
        acc[i][j] = __builtin_amdgcn_mfma_f32_16x16x32_bf16(af[i], bfr[j], acc[i][j], 0, 0, 0);
  }

  float* Co = val_f + (long)batch * 2048 * 1024;
  #pragma unroll
  for (int i = 0; i < 4; i++)
    #pragma unroll
    for (int j = 0; j < 4; j++)
      #pragma unroll
      for (int reg = 0; reg < 4; reg++) {
        const int row = bm + wm * 64 + i * 16 + quad * 4 + reg;
        const int col = bn + wn * 64 + j * 16 + r;
        Co[(long)row * 1024 + col] = acc[i][j][reg];
      }
}

extern "C" void kernel_launch(void* const* d_in, const int* in_sizes, int n_in,
                              void* d_out, int out_size, void* d_ws, size_t ws_size,
                              hipStream_t stream) {
  const float* x   = (const float*)d_in[0];  // (8,2048,256) -> (16384,256)
  const float* mem = (const float*)d_in[1];  // (8,1024,256)
  const float* W   = (const float*)d_in[2];  // (256,256)
  float* out   = (float*)d_out;
  float* key_f = out;            // (16384,256) fp32
  float* val_f = out + NX;       // (8,2048,1024) fp32
  (void)d_ws; (void)ws_size;

  // 1) key = relu(x @ W^T): barrier-free K-loop, W in LDS, x streamed.
  dim3 g1(2, 128, 1);
  gemm1_kernel<<<g1, 256, 0, stream>>>(x, W, key_f);

  // 2) val_b = key_b @ mem_b^T: m97 2-barrier loop, fp32 staging + cvt.
  dim3 g2(8, 16, 8);
  gemm2_kernel<<<g2, 256, 0, stream>>>(key_f, mem, val_f);
}